// Round 2
// baseline (113.399 us; speedup 1.0000x reference)
//
#include <hip/hip_runtime.h>
#include <math.h>

#define NP 30
#define NX 13
#define ROWS 256

__global__ __launch_bounds__(ROWS) void t1d_kernel(
    const float* __restrict__ x,
    const float* __restrict__ params,
    const float* __restrict__ CHO,
    const float* __restrict__ insulin_u,
    const float* __restrict__ last_Qsto,
    const float* __restrict__ last_foodtaken,
    float* __restrict__ out,
    int n)
{
    // Unpadded row-major LDS: LDS index == flat float index within the block's
    // contiguous global chunk, so staging is a straight float4 copy.
    // Read conflicts: stride-30 => 4 lanes/bank (~1.6x, negligible);
    // stride-13 => conflict-free (gcd(13,32)=1).
    __shared__ float lds_p[ROWS * NP];   // 30720 B
    __shared__ float lds_x[ROWS * NX];   // 13312 B (reused for outputs)

    const int tid = threadIdx.x;
    const long long blockStart = (long long)blockIdx.x * ROWS;
    const int nrows = (int)((long long)n - blockStart < ROWS ? (long long)n - blockStart : ROWS);
    if (nrows <= 0) return;

    // ---- stage params & x with fully-coalesced float4 loads ----
    {
        const float* srcp = params + blockStart * NP;   // block offset: 30720*blockIdx B, 16B-aligned
        const int totp = nrows * NP;
        const int pf4 = totp >> 2;
        const float4* s4 = (const float4*)srcp;
        float4* d4 = (float4*)lds_p;
        for (int idx = tid; idx < pf4; idx += ROWS) d4[idx] = s4[idx];
        for (int g = (pf4 << 2) + tid; g < totp; g += ROWS) lds_p[g] = srcp[g];

        const float* srcx = x + blockStart * NX;        // 13312*blockIdx B, 16B-aligned
        const int totx = nrows * NX;
        const int xf4 = totx >> 2;
        const float4* sx4 = (const float4*)srcx;
        float4* dx4 = (float4*)lds_x;
        for (int idx = tid; idx < xf4; idx += ROWS) dx4[idx] = sx4[idx];
        for (int g = (xf4 << 2) + tid; g < totx; g += ROWS) lds_x[g] = srcx[g];
    }
    __syncthreads();

    if (tid < nrows) {
        const int i = (int)(blockStart + tid);
        const float* p = lds_p + tid * NP;
        float kmax = p[0],  kmin = p[1],  b    = p[2],  d_   = p[3];
        float kabs = p[4],  f    = p[5],  BW   = p[6],  kp1  = p[7];
        float kp2  = p[8],  kp3  = p[9],  Fsnc = p[10], ke1  = p[11];
        float ke2  = p[12], k1   = p[13], k2   = p[14], Vm0  = p[15];
        float Vmx  = p[16], Km0  = p[17], m1   = p[18], m2   = p[19];
        float m4   = p[20], m30  = p[21], ka1  = p[22], ka2  = p[23];
        float kd   = p[24], Vi   = p[25], p2u  = p[26], Ib   = p[27];
        float ki   = p[28], ksc  = p[29];

        const float* xr = lds_x + tid * NX;
        float x0 = xr[0], x1 = xr[1], x2 = xr[2], x3 = xr[3], x4 = xr[4];
        float x5 = xr[5], x6 = xr[6], x7 = xr[7], x8 = xr[8], x9 = xr[9];
        float x10 = xr[10], x11 = xr[11], x12 = xr[12];

        float d       = CHO[i] * 1000.0f;               // coalesced stride-1
        float insulin = insulin_u[i] * 6000.0f / BW;

        float qsto = x0 + x1;
        float Dbar = last_Qsto[i] + last_foodtaken[i];  // coalesced stride-1
        bool has_food = Dbar > 0.0f;
        float Dbar_safe = has_food ? Dbar : 1.0f;
        float aa = 2.5f / (1.0f - b) / Dbar_safe;
        float cc = 2.5f / d_ / Dbar_safe;
        float kgut_eating = kmin + (kmax - kmin) * 0.5f *
            (tanhf(aa * (qsto - b * Dbar)) - tanhf(cc * (qsto - d_ * Dbar)) + 2.0f);
        float kgut = has_food ? kgut_eating : kmax;

        float d0 = -kmax * x0 + d;
        float d1 = kmax * x0 - x1 * kgut;
        float d2 = kgut * x1 - kabs * x2;

        float Rat  = f * kabs * x2 / BW;
        float EGPt = kp1 - kp2 * x3 - kp3 * x8;
        float Uiit = Fsnc;
        float Et   = (x3 > ke2) ? ke1 * (x3 - ke2) : 0.0f;
        float d3 = (fmaxf(EGPt, 0.0f) + Rat - Uiit - Et - k1 * x3 + k2 * x4) *
                   (x3 >= 0.0f ? 1.0f : 0.0f);

        float Vmt  = Vm0 + Vmx * x6;
        float Uidt = Vmt * x4 / (Km0 + x4);
        float d4 = (-Uidt + k1 * x3 - k2 * x4) * (x4 >= 0.0f ? 1.0f : 0.0f);

        float d5 = (-(m2 + m4) * x5 + m1 * x9 + ka1 * x10 + ka2 * x11) *
                   (x5 >= 0.0f ? 1.0f : 0.0f);
        float It = x5 / Vi;
        float d6 = -p2u * x6 + p2u * (It - Ib);
        float d7 = -ki * (x7 - It);
        float d8 = -ki * (x8 - x7);
        float d9  = (-(m1 + m30) * x9 + m2 * x5) * (x9 >= 0.0f ? 1.0f : 0.0f);
        float d10 = (insulin - (ka1 + kd) * x10) * (x10 >= 0.0f ? 1.0f : 0.0f);
        float d11 = (kd * x10 - ka2 * x11) * (x11 >= 0.0f ? 1.0f : 0.0f);
        float d12 = (-ksc * x12 + ksc * x3) * (x12 >= 0.0f ? 1.0f : 0.0f);

        // overwrite own x-row with outputs (no cross-thread hazard: each
        // thread reads/writes only its own 13-float row)
        float* o = lds_x + tid * NX;
        o[0] = d0;  o[1] = d1;  o[2] = d2;  o[3] = d3;  o[4] = d4;
        o[5] = d5;  o[6] = d6;  o[7] = d7;  o[8] = d8;  o[9] = d9;
        o[10] = d10; o[11] = d11; o[12] = d12;
    }
    __syncthreads();

    // ---- coalesced float4 store of the block's contiguous output chunk ----
    {
        float* dst = out + blockStart * NX;
        const int totx = nrows * NX;
        const int xf4 = totx >> 2;
        const float4* s4 = (const float4*)lds_x;
        float4* d4 = (float4*)dst;
        for (int idx = tid; idx < xf4; idx += ROWS) d4[idx] = s4[idx];
        for (int g = (xf4 << 2) + tid; g < totx; g += ROWS) dst[g] = lds_x[g];
    }
}

extern "C" void kernel_launch(void* const* d_in, const int* in_sizes, int n_in,
                              void* d_out, int out_size, void* d_ws, size_t ws_size,
                              hipStream_t stream) {
    const float* x    = (const float*)d_in[0];
    const float* par  = (const float*)d_in[1];
    const float* CHO  = (const float*)d_in[2];
    const float* ins  = (const float*)d_in[3];
    const float* lq   = (const float*)d_in[4];
    const float* lf   = (const float*)d_in[5];
    float* out = (float*)d_out;
    int n = in_sizes[2];  // B (CHO length)

    int block = ROWS;
    int grid = (n + block - 1) / block;
    t1d_kernel<<<grid, block, 0, stream>>>(x, par, CHO, ins, lq, lf, out, n);
}